// Round 1
// baseline (6033.517 us; speedup 1.0000x reference)
//
#include <hip/hip_runtime.h>
#include <math.h>

#define T_ 200
#define WROW 284                       // LDS row stride (256 + swizzle room)
#define SMEM_FLOATS (128 * WROW + 16 * WROW)
#define SMEM_BYTES (SMEM_FLOATS * 4)   // 163,584 <= 163,840 (160 KiB)

__device__ __forceinline__ float fsig(float x) {
  return 1.f / (1.f + __expf(-x));
}
__device__ __forceinline__ float ftanh(float x) {
  return 1.f - 2.f / (__expf(2.f * x) + 1.f);   // exact at +-inf, no NaN
}

// ---------------- xg GEMM v2: 128x128 tile, 8x8 micro, fused embedding gather,
// masked-tile early exit. C[rows x 1024] = emb[rows x 256] @ Wih^T + bias.
// A staged transposed with col swizzle m+((m>>5)<<2) -> 2-way (free) reads.
__global__ __launch_bounds__(256) void xg_gemm(
    const int* __restrict__ bin, const int* __restrict__ bfe,
    const int* __restrict__ blen,
    const float* __restrict__ ctab, const float* __restrict__ ftab,
    const float* __restrict__ wih, const float* __restrict__ bias,
    float* __restrict__ xgslot, int t0, int sgn) {
  const int m0 = blockIdx.x * 128;
  const int rloc = m0 >> 8;
  const int t_blk = t0 + sgn * rloc;
  if (t_blk >= blen[m0 & 255]) return;   // fully masked tile (sorted lengths)

  __shared__ float As[32][140];   // [k][m swizzled]
  __shared__ float Bs[32][132];   // [k][n]
  const int tid = threadIdx.x;
  const int n0 = blockIdx.y * 128;
  const int mm = tid & 15;
  const int nn = tid >> 4;

  const int ra = tid & 127;            // staging row (A: m, B: n)
  const int ka = (tid >> 7) << 4;      // k-offset 0 or 16

  const int bcol = (m0 + ra) & 255;
  const float* cr = ctab + ((size_t)bin[bcol * T_ + t_blk] << 8);
  const float* fr = ftab + ((size_t)bfe[bcol * T_ + t_blk] << 8);
  const float* br = wih + (size_t)(n0 + ra) * 256;
  const int cwa = ra + ((ra >> 5) << 2);   // swizzled A col for m=ra

  float acc[8][8];
  #pragma unroll
  for (int i = 0; i < 8; ++i)
    #pragma unroll
    for (int j = 0; j < 8; ++j) acc[i][j] = 0.f;

  const int am0 = mm * 8 + ((mm >> 2) << 2);   // swizzled base col for A reads
  const int bn0 = nn * 8;

  for (int ks = 0; ks < 256; ks += 32) {
    float4 c4[4], f4v[4], b4[4];
    #pragma unroll
    for (int w = 0; w < 4; ++w) {
      c4[w]  = *(const float4*)(cr + ks + ka + w * 4);
      f4v[w] = *(const float4*)(fr + ks + ka + w * 4);
      b4[w]  = *(const float4*)(br + ks + ka + w * 4);
    }
    __syncthreads();   // previous iteration's consumers done
    #pragma unroll
    for (int w = 0; w < 4; ++w) {
      int kk = ka + w * 4;
      As[kk + 0][cwa] = c4[w].x * f4v[w].x;
      As[kk + 1][cwa] = c4[w].y * f4v[w].y;
      As[kk + 2][cwa] = c4[w].z * f4v[w].z;
      As[kk + 3][cwa] = c4[w].w * f4v[w].w;
      Bs[kk + 0][ra] = b4[w].x;
      Bs[kk + 1][ra] = b4[w].y;
      Bs[kk + 2][ra] = b4[w].z;
      Bs[kk + 3][ra] = b4[w].w;
    }
    __syncthreads();
    #pragma unroll 4
    for (int k = 0; k < 32; ++k) {
      float4 a0 = *(const float4*)&As[k][am0];
      float4 a1 = *(const float4*)&As[k][am0 + 4];
      float4 b0 = *(const float4*)&Bs[k][bn0];
      float4 b1 = *(const float4*)&Bs[k][bn0 + 4];
      float am[8] = {a0.x, a0.y, a0.z, a0.w, a1.x, a1.y, a1.z, a1.w};
      float bn[8] = {b0.x, b0.y, b0.z, b0.w, b1.x, b1.y, b1.z, b1.w};
      #pragma unroll
      for (int i = 0; i < 8; ++i)
        #pragma unroll
        for (int j = 0; j < 8; ++j)
          acc[i][j] += am[i] * bn[j];
    }
  }

  float4 bv0 = *(const float4*)(bias + n0 + bn0);
  float4 bv1 = *(const float4*)(bias + n0 + bn0 + 4);
  #pragma unroll
  for (int i = 0; i < 8; ++i) {
    int row = m0 + mm * 8 + i;
    float4 o0, o1;
    o0.x = acc[i][0] + bv0.x; o0.y = acc[i][1] + bv0.y;
    o0.z = acc[i][2] + bv0.z; o0.w = acc[i][3] + bv0.w;
    o1.x = acc[i][4] + bv1.x; o1.y = acc[i][5] + bv1.y;
    o1.z = acc[i][6] + bv1.z; o1.w = acc[i][7] + bv1.w;
    *(float4*)(xgslot + (size_t)row * 1024 + n0 + bn0) = o0;
    *(float4*)(xgslot + (size_t)row * 1024 + n0 + bn0 + 4) = o1;
  }
}

// ---------------- persistent LSTM chunk v5: r8 sync restructure.
// Same compute core (ks8/bg4/rg16, W in LDS, agent-scope h exchange) as the
// proven v4, with the per-step protocol rebuilt to cut critical-path latency:
//   * two-level arrival: per-wave vmcnt(0) drain -> LDS tally; the LAST wave
//     to tally publishes the group arrival (bar += 8). No pre-add syncthreads,
//     no block-serialized drain.
//   * two-hop release: wave0 polls the global counter (8 pollers/line, same
//     contention as v4) and publishes to an LDS flag; waves 1..7 spin on LDS.
//     No post-poll syncthreads. Safe because bar >= 64*s implies every wave of
//     every group block finished its hlds reads for step s-1 (arrival comes
//     after the GEMM reads in program order).
//   * xq prefetched one step ahead (issued after the staging sync, lands under
//     the GEMM), so the staging vmcnt(0) only waits the two L2/L3 h vectors,
//     never HBM.
// One syncthreads per step (cross-wave hlds RAW) instead of three.
__global__ __launch_bounds__(512, 1) void lstm_chunk(
    const float* __restrict__ xgf, const float* __restrict__ xgb,
    const float* __restrict__ whf, const float* __restrict__ whb,
    const int* __restrict__ blen,
    float* __restrict__ hst, float* __restrict__ cst,
    float* __restrict__ hout, unsigned* __restrict__ bar,
    int s0, int nsteps) {
  extern __shared__ float smem[];
  float* wlds = smem;                 // [128][WROW]
  float* hlds = smem + 128 * WROW;    // [16][WROW]
  __shared__ unsigned hcnt;           // block-local wave-arrival tally
  __shared__ unsigned gflag;          // block-local released-step flag

  const int bc = blockIdx.x, js = blockIdx.y, dir = blockIdx.z;
  const int tid = threadIdx.x;
  const int ks = tid & 7;
  const int bg = (tid >> 3) & 3;
  const int rg = tid >> 5;            // 0..15
  const int grp = dir * 16 + bc;
  const float* wh = dir ? whb : whf;
  const float* xgp = dir ? xgb : xgf;
  unsigned* __restrict__ barp = bar + grp * 32;

  if (tid == 0) { hcnt = 0u; gflag = 0u; }

  // ---- stage W once per chunk (permuted rows: prow = rgs*8 + g*2 + u)
  #pragma unroll
  for (int i = 0; i < 16; ++i) {
    int f = tid + i * 512;            // float4 id 0..8191
    int prow = f >> 6;
    int k = (f & 63) << 2;
    int g = (prow >> 1) & 3, u = prow & 1, rgs = prow >> 3;
    int jg = js * 32 + rgs * 2 + u;
    float4 v = *(const float4*)(wh + ((size_t)(g * 256 + jg)) * 256 + k);
    *(float4*)&wlds[prow * WROW + k + ((k >> 5) << 2)] = v;
  }

  const int bl_th = bg * 4 + (ks & 3);      // local batch 0..15
  const int b_th = bc * 16 + bl_th;         // global batch
  const int u_th = ks >> 2;
  const int jth = js * 32 + rg * 2 + u_th;  // this thread's j
  const int cjth = jth + ((jth >> 5) << 2); // swizzled col of jth
  const int len_th = blen[b_th];
  float c0 = cst[((size_t)dir * 256 + b_th) * 256 + jth];

  // ---- prologue xq (r = 0) — latency hidden under W staging
  float xq[4];
  #pragma unroll
  for (int g = 0; g < 4; ++g)
    xq[g] = xgp[(size_t)b_th * 1024 + g * 256 + jth];

  __syncthreads();   // W staged, hcnt/gflag init visible

  for (int r = 0; r < nsteps; ++r) {
    const int s = s0 + r;
    const int tt = dir ? (199 - s) : s;
    const int rslot = s & 1, wslot = 1 - rslot;

    // ---- wait for h(s-1): wave0 polls global, fans out via LDS flag
    if (tid < 64) {
      const unsigned tgt = 64u * (unsigned)s;
      while (__hip_atomic_load(barp, __ATOMIC_RELAXED,
                               __HIP_MEMORY_SCOPE_AGENT) < tgt) {}
      if (tid == 0)
        __hip_atomic_store(&gflag, (unsigned)(r + 1), __ATOMIC_RELAXED,
                           __HIP_MEMORY_SCOPE_WORKGROUP);
    } else {
      while (__hip_atomic_load(&gflag, __ATOMIC_RELAXED,
                               __HIP_MEMORY_SCOPE_WORKGROUP) <
             (unsigned)(r + 1)) {}
    }

    // ---- stage h[16 b][256 k]: 2 agent-scope (sc1) dwordx4 per thread.
    // vmcnt(0) here waits only these 2 loads (+ the already-retired hout
    // store / xq prefetch from the previous step).
    const float* hsrc = hst + (((size_t)(rslot * 2 + dir)) * 256 + bc * 16) * 256;
    {
      const int f0 = tid, f1 = tid + 512;        // float4 ids
      const int b0i = f0 >> 6, k0 = (f0 & 63) << 2;
      const int b1i = f1 >> 6, k1 = (f1 & 63) << 2;
      const float* p0 = hsrc + (b0i << 8) + k0;
      const float* p1 = hsrc + (b1i << 8) + k1;
      float4 v0, v1;
      asm volatile(
          "global_load_dwordx4 %0, %2, off sc1\n\t"
          "global_load_dwordx4 %1, %3, off sc1\n\t"
          "s_waitcnt vmcnt(0)"
          : "=&v"(v0), "=&v"(v1)
          : "v"(p0), "v"(p1)
          : "memory");
      *(float4*)&hlds[b0i * WROW + k0 + ((k0 >> 5) << 2)] = v0;
      *(float4*)&hlds[b1i * WROW + k1 + ((k1 >> 5) << 2)] = v1;
    }
    __syncthreads();   // cross-wave hlds RAW (the one barrier per step)

    // ---- prefetch next step's xq; lands under the GEMM
    float xqn[4];
    const int rn = (r + 1 < nsteps) ? (r + 1) : r;
    #pragma unroll
    for (int g = 0; g < 4; ++g)
      xqn[g] = xgp[((size_t)rn * 256 + b_th) * 1024 + g * 256 + jth];

    // ---- GEMM: acc[i][bb], i = gate-pair row, bb = batch within quad
    float acc[8][4];
    #pragma unroll
    for (int i = 0; i < 8; ++i)
      #pragma unroll
      for (int bb = 0; bb < 4; ++bb) acc[i][bb] = 0.f;

    #pragma unroll
    for (int kq = 0; kq < 8; ++kq) {
      const int col = ks * 36 + kq * 4;
      float4 h4[4];
      #pragma unroll
      for (int bb = 0; bb < 4; ++bb)
        h4[bb] = *(const float4*)&hlds[(bg * 4 + bb) * WROW + col];
      #pragma unroll
      for (int i = 0; i < 8; ++i) {
        float4 w4 = *(const float4*)&wlds[(rg * 8 + i) * WROW + col];
        #pragma unroll
        for (int bb = 0; bb < 4; ++bb)
          acc[i][bb] += w4.x * h4[bb].x + w4.y * h4[bb].y +
                        w4.z * h4[bb].z + w4.w * h4[bb].w;
      }
    }

    // ---- butterfly over ks: xor1/xor2 route batches, xor4 finishes k-reduce
    const int bit0 = ks & 1, bit1 = (ks >> 1) & 1;
    float fin[8];
    #pragma unroll
    for (int i = 0; i < 8; ++i) {
      float k0 = bit0 ? acc[i][1] : acc[i][0];
      float s0v = bit0 ? acc[i][0] : acc[i][1];
      float k1 = bit0 ? acc[i][3] : acc[i][2];
      float s1v = bit0 ? acc[i][2] : acc[i][3];
      float r0 = k0 + __shfl_xor(s0v, 1);
      float r1 = k1 + __shfl_xor(s1v, 1);
      float k2 = bit1 ? r1 : r0;
      float s2v = bit1 ? r0 : r1;
      float r2 = k2 + __shfl_xor(s2v, 2);
      fin[i] = r2 + __shfl_xor(r2, 4);
    }

    // ---- cell update (1 cell per thread: batch b_th, hidden jth)
    float gi = fsig((u_th ? fin[1] : fin[0]) + xq[0]);
    float gf = fsig((u_th ? fin[3] : fin[2]) + xq[1]);
    float gg = ftanh((u_th ? fin[5] : fin[4]) + xq[2]);
    float go = fsig((u_th ? fin[7] : fin[6]) + xq[3]);
    float cn = gf * c0 + gi * gg;
    float hn = go * ftanh(cn);
    const bool mk = tt < len_th;
    if (mk) c0 = cn;
    float hold = hlds[bl_th * WROW + cjth];
    float hsv = mk ? hn : hold;
    __hip_atomic_store(
        hst + (((size_t)(wslot * 2 + dir)) * 256 + b_th) * 256 + jth,
        hsv, __ATOMIC_RELAXED, __HIP_MEMORY_SCOPE_AGENT);

    // ---- per-wave drain; last wave to tally publishes the group arrival.
    asm volatile("s_waitcnt vmcnt(0)" ::: "memory");
    if ((tid & 63) == 0) {
      unsigned prev = __hip_atomic_fetch_add(&hcnt, 1u, __ATOMIC_RELAXED,
                                             __HIP_MEMORY_SCOPE_WORKGROUP);
      if (prev == (unsigned)(8 * r + 7))
        __hip_atomic_fetch_add(barp, 8u, __ATOMIC_RELAXED,
                               __HIP_MEMORY_SCOPE_AGENT);
    }
    // hout store overlaps the next poll; not part of the h protocol.
    hout[(((size_t)dir * 200 + tt) * 256 + b_th) * 256 + jth] = mk ? hn : 0.f;

    #pragma unroll
    for (int g = 0; g < 4; ++g) xq[g] = xqn[g];
  }

  cst[((size_t)dir * 256 + b_th) * 256 + jth] = c0;
}

// ---------------- feats[b][t][k] = [hf|hb] . W_tag[k] + b_tag[k]  (r2, proven)
__global__ __launch_bounds__(256) void feats_kernel(
    const float* __restrict__ h_out, const float* __restrict__ wtag,
    const float* __restrict__ btag, float* __restrict__ feats) {
  __shared__ float hcat[32][512];
  const int t = blockIdx.x, bc = blockIdx.y;
  const int tid = threadIdx.x;
  const float* hf = h_out + (((size_t)0 * 200 + t) * 256 + bc * 32) * 256;
  const float* hb = h_out + (((size_t)1 * 200 + t) * 256 + bc * 32) * 256;
  for (int i = tid; i < 2048; i += 256) {
    int row = i >> 6, c4 = (i & 63) << 2;
    *(float4*)&hcat[row][c4] = *(const float4*)(hf + (size_t)row * 256 + c4);
    *(float4*)&hcat[row][256 + c4] = *(const float4*)(hb + (size_t)row * 256 + c4);
  }
  __syncthreads();
  const int kk = tid & 63;
  const int bg = tid >> 6;
  if (kk < 52) {
    float acc[8];
    #pragma unroll
    for (int i = 0; i < 8; ++i) acc[i] = 0.f;
    const float* wr = wtag + (size_t)kk * 512;
    for (int jq = 0; jq < 128; ++jq) {
      float4 wv = *(const float4*)(wr + jq * 4);
      #pragma unroll
      for (int bi = 0; bi < 8; ++bi) {
        float4 hv = *(const float4*)&hcat[bg * 8 + bi][jq * 4];
        acc[bi] += wv.x * hv.x + wv.y * hv.y + wv.z * hv.z + wv.w * hv.w;
      }
    }
    float bv = btag[kk];
    #pragma unroll
    for (int bi = 0; bi < 8; ++bi)
      feats[(size_t)(bc * 32 + bg * 8 + bi) * 10400 + t * 52 + kk] = acc[bi] + bv;
  }
}

// ---------------- Viterbi v3 (r7, passed): one WAVE per batch row.
__global__ __launch_bounds__(64) void viterbi_kernel(
    const float* __restrict__ feats, const float* __restrict__ trans,
    const int* __restrict__ blen, float* __restrict__ out) {
  __shared__ float flds[10400];
  __shared__ float pl[56];
  __shared__ unsigned char bp[199 * 52];

  const int b = blockIdx.x;
  const int lane = threadIdx.x;
  const int kk = (lane < 52) ? lane : 0;
  const float* fb = feats + (size_t)b * 10400;
  const int len = blen[b];

  for (int i = lane; i < 2600; i += 64)
    *(float4*)&flds[i * 4] = *(const float4*)(fb + i * 4);

  float trc[52];
  #pragma unroll
  for (int j = 0; j < 52; ++j) trc[j] = trans[j * 52 + kk];
  __syncthreads();

  float part = trans[50 * 52 + kk] + flds[kk];   // START row = 50
  if (lane < 52) pl[lane] = part;

  for (int t = 1; t < 200; ++t) {
    const float ftk = flds[t * 52 + kk];
    float pa[52];
    #pragma unroll
    for (int q = 0; q < 13; ++q) {
      float4 v = *(const float4*)&pl[q * 4];
      pa[q * 4 + 0] = v.x; pa[q * 4 + 1] = v.y;
      pa[q * 4 + 2] = v.z; pa[q * 4 + 3] = v.w;
    }
    float mv0 = -1e30f, mv1 = -1e30f, mv2 = -1e30f, mv3 = -1e30f;
    int mj0 = 0, mj1 = 13, mj2 = 26, mj3 = 39;
    #pragma unroll
    for (int q = 0; q < 13; ++q) {
      float c0v = (pa[q] + trc[q]) + ftk;
      if (c0v > mv0) { mv0 = c0v; mj0 = q; }
      float c1v = (pa[13 + q] + trc[13 + q]) + ftk;
      if (c1v > mv1) { mv1 = c1v; mj1 = 13 + q; }
      float c2v = (pa[26 + q] + trc[26 + q]) + ftk;
      if (c2v > mv2) { mv2 = c2v; mj2 = 26 + q; }
      float c3v = (pa[39 + q] + trc[39 + q]) + ftk;
      if (c3v > mv3) { mv3 = c3v; mj3 = 39 + q; }
    }
    float mv = mv0; int mj = mj0;
    if (mv1 > mv) { mv = mv1; mj = mj1; }
    if (mv2 > mv) { mv = mv2; mj = mj2; }
    if (mv3 > mv) { mv = mv3; mj = mj3; }
    const bool m = t < len;
    if (lane < 52) {
      bp[(t - 1) * 52 + lane] = (unsigned char)(m ? mj : lane);
      if (m) { part = mv; pl[lane] = mv; }
    }
  }

  float fin = (lane < 52) ? (part + trans[lane * 52 + 51]) : -1e30f;
  int bi = lane;
  #pragma unroll
  for (int off = 32; off; off >>= 1) {
    float ov = __shfl_down(fin, off);
    int oi = __shfl_down(bi, off);
    if (ov > fin || (ov == fin && oi < bi)) { fin = ov; bi = oi; }
  }
  if (lane == 0) {
    out[b] = fin;
    int tag = bi;
    float* dec = out + 256 + (size_t)b * 200;
    dec[199] = (199 < len) ? (float)tag : 0.f;
    for (int i = 198; i >= 0; --i) {
      tag = bp[i * 52 + tag];
      dec[i] = (i < len) ? (float)tag : 0.f;
    }
  }
}

extern "C" void kernel_launch(void* const* d_in, const int* in_sizes, int n_in,
                              void* d_out, int out_size, void* d_ws, size_t ws_size,
                              hipStream_t stream) {
  const int*   bin  = (const int*)d_in[0];
  const int*   bfe  = (const int*)d_in[1];
  const int*   blen = (const int*)d_in[2];
  const float* ctab = (const float*)d_in[5];
  const float* ftab = (const float*)d_in[6];
  const float* wihf = (const float*)d_in[7];
  const float* whhf = (const float*)d_in[8];
  const float* bf   = (const float*)d_in[9];
  const float* wihb = (const float*)d_in[10];
  const float* whhb = (const float*)d_in[11];
  const float* bb   = (const float*)d_in[12];
  const float* wtag = (const float*)d_in[13];
  const float* btag = (const float*)d_in[14];
  const float* trn  = (const float*)d_in[15];

  (void)hipFuncSetAttribute(reinterpret_cast<const void*>(lstm_chunk),
                            hipFuncAttributeMaxDynamicSharedMemorySize,
                            SMEM_BYTES);

  const size_t FIXED_F = 29271040;
  size_t ws_f = ws_size / sizeof(float);
  int C = 1;
  const int cands[10] = {50, 40, 25, 20, 10, 8, 5, 4, 2, 1};
  for (int u = 0; u < 10; ++u) {
    if (FIXED_F + (size_t)2 * cands[u] * 262144 <= ws_f) { C = cands[u]; break; }
  }

  float* ws  = (float*)d_ws;
  float* xgf = ws;
  float* xgb = xgf + (size_t)C * 262144;
  float* hst = xgb + (size_t)C * 262144;    // 2 slots x 2 dir x 256 x 256
  float* cst = hst + 262144;
  float* hout = cst + 131072;               // 2 dir x 200 x 256 x 256
  float* fts  = hout + 26214400;
  unsigned* bar = (unsigned*)(fts + 2662400); // 32 groups x stride 32
  float* out  = (float*)d_out;

  hipMemsetAsync(hst, 0, (size_t)(262144 + 131072) * sizeof(float), stream);
  hipMemsetAsync(bar, 0, 1024 * sizeof(unsigned), stream);

  const int nchunks = 200 / C;
  for (int c = 0; c < nchunks; ++c) {
    xg_gemm<<<dim3(2 * C, 8), 256, 0, stream>>>(bin, bfe, blen, ctab, ftab,
                                                wihf, bf, xgf, c * C, 1);
    xg_gemm<<<dim3(2 * C, 8), 256, 0, stream>>>(bin, bfe, blen, ctab, ftab,
                                                wihb, bb, xgb, 199 - c * C, -1);
    lstm_chunk<<<dim3(16, 8, 2), 512, SMEM_BYTES, stream>>>(
        xgf, xgb, whhf, whhb, blen, hst, cst, hout, bar, c * C, C);
  }
  feats_kernel<<<dim3(200, 8), 256, 0, stream>>>(hout, wtag, btag, fts);
  viterbi_kernel<<<256, 64, 0, stream>>>(fts, trn, blen, out);
}

// Round 2
// 2428.565 us; speedup vs baseline: 2.4844x; 2.4844x over previous
//
#include <hip/hip_runtime.h>
#include <math.h>

#define T_ 200
#define WROW 284                       // LDS row stride (256 + swizzle room)
#define SMEM_FLOATS (128 * WROW + 16 * WROW)
#define SMEM_BYTES (SMEM_FLOATS * 4)   // 163,584 <= 163,840 (160 KiB)

__device__ __forceinline__ float fsig(float x) {
  return 1.f / (1.f + __expf(-x));
}
__device__ __forceinline__ float ftanh(float x) {
  return 1.f - 2.f / (__expf(2.f * x) + 1.f);   // exact at +-inf, no NaN
}

// ---------------- xg GEMM v2: 128x128 tile, 8x8 micro, fused embedding gather,
// masked-tile early exit. C[rows x 1024] = emb[rows x 256] @ Wih^T + bias.
// A staged transposed with col swizzle m+((m>>5)<<2) -> 2-way (free) reads.
__global__ __launch_bounds__(256) void xg_gemm(
    const int* __restrict__ bin, const int* __restrict__ bfe,
    const int* __restrict__ blen,
    const float* __restrict__ ctab, const float* __restrict__ ftab,
    const float* __restrict__ wih, const float* __restrict__ bias,
    float* __restrict__ xgslot, int t0, int sgn) {
  const int m0 = blockIdx.x * 128;
  const int rloc = m0 >> 8;
  const int t_blk = t0 + sgn * rloc;
  if (t_blk >= blen[m0 & 255]) return;   // fully masked tile (sorted lengths)

  __shared__ float As[32][140];   // [k][m swizzled]
  __shared__ float Bs[32][132];   // [k][n]
  const int tid = threadIdx.x;
  const int n0 = blockIdx.y * 128;
  const int mm = tid & 15;
  const int nn = tid >> 4;

  const int ra = tid & 127;            // staging row (A: m, B: n)
  const int ka = (tid >> 7) << 4;      // k-offset 0 or 16

  const int bcol = (m0 + ra) & 255;
  const float* cr = ctab + ((size_t)bin[bcol * T_ + t_blk] << 8);
  const float* fr = ftab + ((size_t)bfe[bcol * T_ + t_blk] << 8);
  const float* br = wih + (size_t)(n0 + ra) * 256;
  const int cwa = ra + ((ra >> 5) << 2);   // swizzled A col for m=ra

  float acc[8][8];
  #pragma unroll
  for (int i = 0; i < 8; ++i)
    #pragma unroll
    for (int j = 0; j < 8; ++j) acc[i][j] = 0.f;

  const int am0 = mm * 8 + ((mm >> 2) << 2);   // swizzled base col for A reads
  const int bn0 = nn * 8;

  for (int ks = 0; ks < 256; ks += 32) {
    float4 c4[4], f4v[4], b4[4];
    #pragma unroll
    for (int w = 0; w < 4; ++w) {
      c4[w]  = *(const float4*)(cr + ks + ka + w * 4);
      f4v[w] = *(const float4*)(fr + ks + ka + w * 4);
      b4[w]  = *(const float4*)(br + ks + ka + w * 4);
    }
    __syncthreads();   // previous iteration's consumers done
    #pragma unroll
    for (int w = 0; w < 4; ++w) {
      int kk = ka + w * 4;
      As[kk + 0][cwa] = c4[w].x * f4v[w].x;
      As[kk + 1][cwa] = c4[w].y * f4v[w].y;
      As[kk + 2][cwa] = c4[w].z * f4v[w].z;
      As[kk + 3][cwa] = c4[w].w * f4v[w].w;
      Bs[kk + 0][ra] = b4[w].x;
      Bs[kk + 1][ra] = b4[w].y;
      Bs[kk + 2][ra] = b4[w].z;
      Bs[kk + 3][ra] = b4[w].w;
    }
    __syncthreads();
    #pragma unroll 4
    for (int k = 0; k < 32; ++k) {
      float4 a0 = *(const float4*)&As[k][am0];
      float4 a1 = *(const float4*)&As[k][am0 + 4];
      float4 b0 = *(const float4*)&Bs[k][bn0];
      float4 b1 = *(const float4*)&Bs[k][bn0 + 4];
      float am[8] = {a0.x, a0.y, a0.z, a0.w, a1.x, a1.y, a1.z, a1.w};
      float bn[8] = {b0.x, b0.y, b0.z, b0.w, b1.x, b1.y, b1.z, b1.w};
      #pragma unroll
      for (int i = 0; i < 8; ++i)
        #pragma unroll
        for (int j = 0; j < 8; ++j)
          acc[i][j] += am[i] * bn[j];
    }
  }

  float4 bv0 = *(const float4*)(bias + n0 + bn0);
  float4 bv1 = *(const float4*)(bias + n0 + bn0 + 4);
  #pragma unroll
  for (int i = 0; i < 8; ++i) {
    int row = m0 + mm * 8 + i;
    float4 o0, o1;
    o0.x = acc[i][0] + bv0.x; o0.y = acc[i][1] + bv0.y;
    o0.z = acc[i][2] + bv0.z; o0.w = acc[i][3] + bv0.w;
    o1.x = acc[i][4] + bv1.x; o1.y = acc[i][5] + bv1.y;
    o1.z = acc[i][6] + bv1.z; o1.w = acc[i][7] + bv1.w;
    *(float4*)(xgslot + (size_t)row * 1024 + n0 + bn0) = o0;
    *(float4*)(xgslot + (size_t)row * 1024 + n0 + bn0 + 4) = o1;
  }
}

// ---------------- persistent LSTM chunk: r7-proven v4 protocol RESTORED
// (ks8/bg4/rg16, W in LDS, 3x syncthreads, tid0 fetch_add + tid0 poll, h via
// agent-scope sc1 dwordx4). r8's two-hop LDS release/tally protocol caused a
// 31.9ms pathological dispatch (spin livelock, FETCH 2x) — do not reintroduce.
// ONE change vs r7: xq is prefetched one step ahead (issued after the staging
// barrier, lands under the GEMM), so the staging vmcnt(0) never waits on
// HBM/L3 xq latency — only the two L2-resident h vectors.
__global__ __launch_bounds__(512, 1) void lstm_chunk(
    const float* __restrict__ xgf, const float* __restrict__ xgb,
    const float* __restrict__ whf, const float* __restrict__ whb,
    const int* __restrict__ blen,
    float* __restrict__ hst, float* __restrict__ cst,
    float* __restrict__ hout, unsigned* __restrict__ bar,
    int s0, int nsteps) {
  extern __shared__ float smem[];
  float* wlds = smem;                 // [128][WROW]
  float* hlds = smem + 128 * WROW;    // [16][WROW]

  const int bc = blockIdx.x, js = blockIdx.y, dir = blockIdx.z;
  const int tid = threadIdx.x;
  const int ks = tid & 7;
  const int bg = (tid >> 3) & 3;
  const int rg = tid >> 5;            // 0..15
  const int grp = dir * 16 + bc;
  const float* wh = dir ? whb : whf;
  const float* xgp = dir ? xgb : xgf;

  // ---- stage W once per chunk (permuted rows: prow = rgs*8 + g*2 + u)
  #pragma unroll
  for (int i = 0; i < 16; ++i) {
    int f = tid + i * 512;            // float4 id 0..8191
    int prow = f >> 6;
    int k = (f & 63) << 2;
    int g = (prow >> 1) & 3, u = prow & 1, rgs = prow >> 3;
    int jg = js * 32 + rgs * 2 + u;
    float4 v = *(const float4*)(wh + ((size_t)(g * 256 + jg)) * 256 + k);
    *(float4*)&wlds[prow * WROW + k + ((k >> 5) << 2)] = v;
  }

  const int bl_th = bg * 4 + (ks & 3);      // local batch 0..15
  const int b_th = bc * 16 + bl_th;         // global batch
  const int u_th = ks >> 2;
  const int jth = js * 32 + rg * 2 + u_th;  // this thread's j
  const int cjth = jth + ((jth >> 5) << 2); // swizzled col of jth
  const int len_th = blen[b_th];
  float c0 = cst[((size_t)dir * 256 + b_th) * 256 + jth];

  // ---- prologue xq (r = 0): latency hidden under W staging
  float xq[4];
  #pragma unroll
  for (int g = 0; g < 4; ++g)
    xq[g] = xgp[(size_t)b_th * 1024 + g * 256 + jth];

  __syncthreads();   // W staged

  for (int r = 0; r < nsteps; ++r) {
    const int s = s0 + r;
    const int tt = dir ? (199 - s) : s;
    const int rslot = s & 1, wslot = 1 - rslot;

    // ---- stage h[16 b][256 k]: 2 agent-scope (sc1) dwordx4 per thread.
    // vmcnt(0) waits only these two loads (xq for this step was prefetched
    // during the PREVIOUS step's GEMM and already drained).
    const float* hsrc = hst + (((size_t)(rslot * 2 + dir)) * 256 + bc * 16) * 256;
    {
      const int f0 = tid, f1 = tid + 512;        // float4 ids
      const int b0i = f0 >> 6, k0 = (f0 & 63) << 2;
      const int b1i = f1 >> 6, k1 = (f1 & 63) << 2;
      const float* p0 = hsrc + (b0i << 8) + k0;
      const float* p1 = hsrc + (b1i << 8) + k1;
      float4 v0, v1;
      asm volatile(
          "global_load_dwordx4 %0, %2, off sc1\n\t"
          "global_load_dwordx4 %1, %3, off sc1\n\t"
          "s_waitcnt vmcnt(0)"
          : "=&v"(v0), "=&v"(v1)
          : "v"(p0), "v"(p1)
          : "memory");
      *(float4*)&hlds[b0i * WROW + k0 + ((k0 >> 5) << 2)] = v0;
      *(float4*)&hlds[b1i * WROW + k1 + ((k1 >> 5) << 2)] = v1;
    }
    __syncthreads();

    // ---- prefetch NEXT step's xq; HBM/L3 latency lands under the GEMM
    float xqn[4];
    const int rn = (r + 1 < nsteps) ? (r + 1) : r;
    #pragma unroll
    for (int g = 0; g < 4; ++g)
      xqn[g] = xgp[((size_t)rn * 256 + b_th) * 1024 + g * 256 + jth];

    // ---- GEMM: acc[i][bb], i = gate-pair row, bb = batch within quad
    float acc[8][4];
    #pragma unroll
    for (int i = 0; i < 8; ++i)
      #pragma unroll
      for (int bb = 0; bb < 4; ++bb) acc[i][bb] = 0.f;

    #pragma unroll
    for (int kq = 0; kq < 8; ++kq) {
      const int col = ks * 36 + kq * 4;
      float4 h4[4];
      #pragma unroll
      for (int bb = 0; bb < 4; ++bb)
        h4[bb] = *(const float4*)&hlds[(bg * 4 + bb) * WROW + col];
      #pragma unroll
      for (int i = 0; i < 8; ++i) {
        float4 w4 = *(const float4*)&wlds[(rg * 8 + i) * WROW + col];
        #pragma unroll
        for (int bb = 0; bb < 4; ++bb)
          acc[i][bb] += w4.x * h4[bb].x + w4.y * h4[bb].y +
                        w4.z * h4[bb].z + w4.w * h4[bb].w;
      }
    }

    // ---- butterfly over ks: xor1/xor2 route batches, xor4 finishes k-reduce
    const int bit0 = ks & 1, bit1 = (ks >> 1) & 1;
    float fin[8];
    #pragma unroll
    for (int i = 0; i < 8; ++i) {
      float k0 = bit0 ? acc[i][1] : acc[i][0];
      float s0v = bit0 ? acc[i][0] : acc[i][1];
      float k1 = bit0 ? acc[i][3] : acc[i][2];
      float s1v = bit0 ? acc[i][2] : acc[i][3];
      float r0 = k0 + __shfl_xor(s0v, 1);
      float r1 = k1 + __shfl_xor(s1v, 1);
      float k2 = bit1 ? r1 : r0;
      float s2v = bit1 ? r0 : r1;
      float r2 = k2 + __shfl_xor(s2v, 2);
      fin[i] = r2 + __shfl_xor(r2, 4);
    }

    // ---- cell update (1 cell per thread: batch b_th, hidden jth)
    float gi = fsig((u_th ? fin[1] : fin[0]) + xq[0]);
    float gf = fsig((u_th ? fin[3] : fin[2]) + xq[1]);
    float gg = ftanh((u_th ? fin[5] : fin[4]) + xq[2]);
    float go = fsig((u_th ? fin[7] : fin[6]) + xq[3]);
    float cn = gf * c0 + gi * gg;
    float hn = go * ftanh(cn);
    const bool mk = tt < len_th;
    if (mk) c0 = cn;
    float hold = hlds[bl_th * WROW + cjth];
    float hsv = mk ? hn : hold;
    __hip_atomic_store(
        hst + (((size_t)(wslot * 2 + dir)) * 256 + b_th) * 256 + jth,
        hsv, __ATOMIC_RELAXED, __HIP_MEMORY_SCOPE_AGENT);

    // ---- drain h stores (also retires xqn prefetch), signal, hout store
    // overlaps the poll.  EXACT r7 protocol — do not restructure.
    asm volatile("s_waitcnt vmcnt(0)" ::: "memory");
    __syncthreads();
    if (tid == 0)
      __hip_atomic_fetch_add(&bar[grp * 32], 1u, __ATOMIC_RELAXED,
                             __HIP_MEMORY_SCOPE_AGENT);
    hout[(((size_t)dir * 200 + tt) * 256 + b_th) * 256 + jth] = mk ? hn : 0.f;
    if (tid == 0) {
      const unsigned tgt = 8u * (unsigned)(s + 1);
      while (__hip_atomic_load(&bar[grp * 32], __ATOMIC_RELAXED,
                               __HIP_MEMORY_SCOPE_AGENT) < tgt) {}
    }
    __syncthreads();

    #pragma unroll
    for (int g = 0; g < 4; ++g) xq[g] = xqn[g];
  }

  cst[((size_t)dir * 256 + b_th) * 256 + jth] = c0;
}

// ---------------- feats[b][t][k] = [hf|hb] . W_tag[k] + b_tag[k]  (r2, proven)
__global__ __launch_bounds__(256) void feats_kernel(
    const float* __restrict__ h_out, const float* __restrict__ wtag,
    const float* __restrict__ btag, float* __restrict__ feats) {
  __shared__ float hcat[32][512];
  const int t = blockIdx.x, bc = blockIdx.y;
  const int tid = threadIdx.x;
  const float* hf = h_out + (((size_t)0 * 200 + t) * 256 + bc * 32) * 256;
  const float* hb = h_out + (((size_t)1 * 200 + t) * 256 + bc * 32) * 256;
  for (int i = tid; i < 2048; i += 256) {
    int row = i >> 6, c4 = (i & 63) << 2;
    *(float4*)&hcat[row][c4] = *(const float4*)(hf + (size_t)row * 256 + c4);
    *(float4*)&hcat[row][256 + c4] = *(const float4*)(hb + (size_t)row * 256 + c4);
  }
  __syncthreads();
  const int kk = tid & 63;
  const int bg = tid >> 6;
  if (kk < 52) {
    float acc[8];
    #pragma unroll
    for (int i = 0; i < 8; ++i) acc[i] = 0.f;
    const float* wr = wtag + (size_t)kk * 512;
    for (int jq = 0; jq < 128; ++jq) {
      float4 wv = *(const float4*)(wr + jq * 4);
      #pragma unroll
      for (int bi = 0; bi < 8; ++bi) {
        float4 hv = *(const float4*)&hcat[bg * 8 + bi][jq * 4];
        acc[bi] += wv.x * hv.x + wv.y * hv.y + wv.z * hv.z + wv.w * hv.w;
      }
    }
    float bv = btag[kk];
    #pragma unroll
    for (int bi = 0; bi < 8; ++bi)
      feats[(size_t)(bc * 32 + bg * 8 + bi) * 10400 + t * 52 + kk] = acc[bi] + bv;
  }
}

// ---------------- Viterbi v3 (r7, passed): one WAVE per batch row.
__global__ __launch_bounds__(64) void viterbi_kernel(
    const float* __restrict__ feats, const float* __restrict__ trans,
    const int* __restrict__ blen, float* __restrict__ out) {
  __shared__ float flds[10400];
  __shared__ float pl[56];
  __shared__ unsigned char bp[199 * 52];

  const int b = blockIdx.x;
  const int lane = threadIdx.x;
  const int kk = (lane < 52) ? lane : 0;
  const float* fb = feats + (size_t)b * 10400;
  const int len = blen[b];

  for (int i = lane; i < 2600; i += 64)
    *(float4*)&flds[i * 4] = *(const float4*)(fb + i * 4);

  float trc[52];
  #pragma unroll
  for (int j = 0; j < 52; ++j) trc[j] = trans[j * 52 + kk];
  __syncthreads();

  float part = trans[50 * 52 + kk] + flds[kk];   // START row = 50
  if (lane < 52) pl[lane] = part;

  for (int t = 1; t < 200; ++t) {
    const float ftk = flds[t * 52 + kk];
    float pa[52];
    #pragma unroll
    for (int q = 0; q < 13; ++q) {
      float4 v = *(const float4*)&pl[q * 4];
      pa[q * 4 + 0] = v.x; pa[q * 4 + 1] = v.y;
      pa[q * 4 + 2] = v.z; pa[q * 4 + 3] = v.w;
    }
    float mv0 = -1e30f, mv1 = -1e30f, mv2 = -1e30f, mv3 = -1e30f;
    int mj0 = 0, mj1 = 13, mj2 = 26, mj3 = 39;
    #pragma unroll
    for (int q = 0; q < 13; ++q) {
      float c0v = (pa[q] + trc[q]) + ftk;
      if (c0v > mv0) { mv0 = c0v; mj0 = q; }
      float c1v = (pa[13 + q] + trc[13 + q]) + ftk;
      if (c1v > mv1) { mv1 = c1v; mj1 = 13 + q; }
      float c2v = (pa[26 + q] + trc[26 + q]) + ftk;
      if (c2v > mv2) { mv2 = c2v; mj2 = 26 + q; }
      float c3v = (pa[39 + q] + trc[39 + q]) + ftk;
      if (c3v > mv3) { mv3 = c3v; mj3 = 39 + q; }
    }
    float mv = mv0; int mj = mj0;
    if (mv1 > mv) { mv = mv1; mj = mj1; }
    if (mv2 > mv) { mv = mv2; mj = mj2; }
    if (mv3 > mv) { mv = mv3; mj = mj3; }
    const bool m = t < len;
    if (lane < 52) {
      bp[(t - 1) * 52 + lane] = (unsigned char)(m ? mj : lane);
      if (m) { part = mv; pl[lane] = mv; }
    }
  }

  float fin = (lane < 52) ? (part + trans[lane * 52 + 51]) : -1e30f;
  int bi = lane;
  #pragma unroll
  for (int off = 32; off; off >>= 1) {
    float ov = __shfl_down(fin, off);
    int oi = __shfl_down(bi, off);
    if (ov > fin || (ov == fin && oi < bi)) { fin = ov; bi = oi; }
  }
  if (lane == 0) {
    out[b] = fin;
    int tag = bi;
    float* dec = out + 256 + (size_t)b * 200;
    dec[199] = (199 < len) ? (float)tag : 0.f;
    for (int i = 198; i >= 0; --i) {
      tag = bp[i * 52 + tag];
      dec[i] = (i < len) ? (float)tag : 0.f;
    }
  }
}

extern "C" void kernel_launch(void* const* d_in, const int* in_sizes, int n_in,
                              void* d_out, int out_size, void* d_ws, size_t ws_size,
                              hipStream_t stream) {
  const int*   bin  = (const int*)d_in[0];
  const int*   bfe  = (const int*)d_in[1];
  const int*   blen = (const int*)d_in[2];
  const float* ctab = (const float*)d_in[5];
  const float* ftab = (const float*)d_in[6];
  const float* wihf = (const float*)d_in[7];
  const float* whhf = (const float*)d_in[8];
  const float* bf   = (const float*)d_in[9];
  const float* wihb = (const float*)d_in[10];
  const float* whhb = (const float*)d_in[11];
  const float* bb   = (const float*)d_in[12];
  const float* wtag = (const float*)d_in[13];
  const float* btag = (const float*)d_in[14];
  const float* trn  = (const float*)d_in[15];

  (void)hipFuncSetAttribute(reinterpret_cast<const void*>(lstm_chunk),
                            hipFuncAttributeMaxDynamicSharedMemorySize,
                            SMEM_BYTES);

  const size_t FIXED_F = 29271040;
  size_t ws_f = ws_size / sizeof(float);
  int C = 1;
  const int cands[10] = {50, 40, 25, 20, 10, 8, 5, 4, 2, 1};
  for (int u = 0; u < 10; ++u) {
    if (FIXED_F + (size_t)2 * cands[u] * 262144 <= ws_f) { C = cands[u]; break; }
  }

  float* ws  = (float*)d_ws;
  float* xgf = ws;
  float* xgb = xgf + (size_t)C * 262144;
  float* hst = xgb + (size_t)C * 262144;    // 2 slots x 2 dir x 256 x 256
  float* cst = hst + 262144;
  float* hout = cst + 131072;               // 2 dir x 200 x 256 x 256
  float* fts  = hout + 26214400;
  unsigned* bar = (unsigned*)(fts + 2662400); // 32 groups x stride 32
  float* out  = (float*)d_out;

  hipMemsetAsync(hst, 0, (size_t)(262144 + 131072) * sizeof(float), stream);
  hipMemsetAsync(bar, 0, 1024 * sizeof(unsigned), stream);

  const int nchunks = 200 / C;
  for (int c = 0; c < nchunks; ++c) {
    xg_gemm<<<dim3(2 * C, 8), 256, 0, stream>>>(bin, bfe, blen, ctab, ftab,
                                                wihf, bf, xgf, c * C, 1);
    xg_gemm<<<dim3(2 * C, 8), 256, 0, stream>>>(bin, bfe, blen, ctab, ftab,
                                                wihb, bb, xgb, 199 - c * C, -1);
    lstm_chunk<<<dim3(16, 8, 2), 512, SMEM_BYTES, stream>>>(
        xgf, xgb, whhf, whhb, blen, hst, cst, hout, bar, c * C, C);
  }
  feats_kernel<<<dim3(200, 8), 256, 0, stream>>>(hout, wtag, btag, fts);
  viterbi_kernel<<<256, 64, 0, stream>>>(fts, trn, blen, out);
}

// Round 3
// 2242.605 us; speedup vs baseline: 2.6904x; 1.0829x over previous
//
#include <hip/hip_runtime.h>
#include <math.h>

#define T_ 200
#define WROW 284                       // LDS row stride (256 + swizzle room)
#define SMEM_FLOATS (128 * WROW + 16 * WROW)
#define SMEM_BYTES (SMEM_FLOATS * 4)   // 163,584 <= 163,840 (160 KiB)

typedef float f32x2 __attribute__((ext_vector_type(2)));

__device__ __forceinline__ float fsig(float x) {
  return 1.f / (1.f + __expf(-x));
}
__device__ __forceinline__ float ftanh(float x) {
  return 1.f - 2.f / (__expf(2.f * x) + 1.f);   // exact at +-inf, no NaN
}

// ---------------- xg GEMM v3: 128x128 tile, 8x8 micro, fused embedding gather,
// masked-tile early exit. r10: inner loop uses v_pk_fma_f32 (j-paired — each
// output's k accumulation order unchanged). 32 pk-FMA + 8 splats per k vs 64
// scalar FMA.
__global__ __launch_bounds__(256) void xg_gemm(
    const int* __restrict__ bin, const int* __restrict__ bfe,
    const int* __restrict__ blen,
    const float* __restrict__ ctab, const float* __restrict__ ftab,
    const float* __restrict__ wih, const float* __restrict__ bias,
    float* __restrict__ xgslot, int t0, int sgn) {
  const int m0 = blockIdx.x * 128;
  const int rloc = m0 >> 8;
  const int t_blk = t0 + sgn * rloc;
  if (t_blk >= blen[m0 & 255]) return;   // fully masked tile (sorted lengths)

  __shared__ float As[32][140];   // [k][m swizzled]
  __shared__ float Bs[32][132];   // [k][n]
  const int tid = threadIdx.x;
  const int n0 = blockIdx.y * 128;
  const int mm = tid & 15;
  const int nn = tid >> 4;

  const int ra = tid & 127;            // staging row (A: m, B: n)
  const int ka = (tid >> 7) << 4;      // k-offset 0 or 16

  const int bcol = (m0 + ra) & 255;
  const float* cr = ctab + ((size_t)bin[bcol * T_ + t_blk] << 8);
  const float* fr = ftab + ((size_t)bfe[bcol * T_ + t_blk] << 8);
  const float* br = wih + (size_t)(n0 + ra) * 256;
  const int cwa = ra + ((ra >> 5) << 2);   // swizzled A col for m=ra

  f32x2 acc[8][4];                      // [i][j-pair]
  #pragma unroll
  for (int i = 0; i < 8; ++i)
    #pragma unroll
    for (int j = 0; j < 4; ++j) acc[i][j] = (f32x2){0.f, 0.f};

  const int am0 = mm * 8 + ((mm >> 2) << 2);   // swizzled base col for A reads
  const int bn0 = nn * 8;

  for (int ks = 0; ks < 256; ks += 32) {
    float4 c4[4], f4v[4], b4[4];
    #pragma unroll
    for (int w = 0; w < 4; ++w) {
      c4[w]  = *(const float4*)(cr + ks + ka + w * 4);
      f4v[w] = *(const float4*)(fr + ks + ka + w * 4);
      b4[w]  = *(const float4*)(br + ks + ka + w * 4);
    }
    __syncthreads();   // previous iteration's consumers done
    #pragma unroll
    for (int w = 0; w < 4; ++w) {
      int kk = ka + w * 4;
      As[kk + 0][cwa] = c4[w].x * f4v[w].x;
      As[kk + 1][cwa] = c4[w].y * f4v[w].y;
      As[kk + 2][cwa] = c4[w].z * f4v[w].z;
      As[kk + 3][cwa] = c4[w].w * f4v[w].w;
      Bs[kk + 0][ra] = b4[w].x;
      Bs[kk + 1][ra] = b4[w].y;
      Bs[kk + 2][ra] = b4[w].z;
      Bs[kk + 3][ra] = b4[w].w;
    }
    __syncthreads();
    #pragma unroll 4
    for (int k = 0; k < 32; ++k) {
      float4 a0 = *(const float4*)&As[k][am0];
      float4 a1 = *(const float4*)&As[k][am0 + 4];
      float4 b0 = *(const float4*)&Bs[k][bn0];
      float4 b1 = *(const float4*)&Bs[k][bn0 + 4];
      float am[8] = {a0.x, a0.y, a0.z, a0.w, a1.x, a1.y, a1.z, a1.w};
      f32x2 bp[4] = {{b0.x, b0.y}, {b0.z, b0.w}, {b1.x, b1.y}, {b1.z, b1.w}};
      #pragma unroll
      for (int i = 0; i < 8; ++i) {
        f32x2 av = {am[i], am[i]};
        #pragma unroll
        for (int j = 0; j < 4; ++j)
          acc[i][j] = __builtin_elementwise_fma(av, bp[j], acc[i][j]);
      }
    }
  }

  float4 bv0 = *(const float4*)(bias + n0 + bn0);
  float4 bv1 = *(const float4*)(bias + n0 + bn0 + 4);
  #pragma unroll
  for (int i = 0; i < 8; ++i) {
    int row = m0 + mm * 8 + i;
    float4 o0, o1;
    o0.x = acc[i][0].x + bv0.x; o0.y = acc[i][0].y + bv0.y;
    o0.z = acc[i][1].x + bv0.z; o0.w = acc[i][1].y + bv0.w;
    o1.x = acc[i][2].x + bv1.x; o1.y = acc[i][2].y + bv1.y;
    o1.z = acc[i][3].x + bv1.z; o1.w = acc[i][3].y + bv1.w;
    *(float4*)(xgslot + (size_t)row * 1024 + n0 + bn0) = o0;
    *(float4*)(xgslot + (size_t)row * 1024 + n0 + bn0 + 4) = o1;
  }
}

// ---------------- persistent LSTM chunk: r7-proven v4 protocol (3x
// syncthreads, tid0 fetch_add + tid0 poll, agent-scope sc1 h exchange) +
// r9 xq-prefetch. r10: h-GEMM inner loop via v_pk_fma_f32 — each k-chain is
// split into lo/hi partial sums ((x,z,..)+(y,w,..)), halving VALU issue from
// 1024 to 512 FMA instructions per thread per step.
__global__ __launch_bounds__(512, 1) void lstm_chunk(
    const float* __restrict__ xgf, const float* __restrict__ xgb,
    const float* __restrict__ whf, const float* __restrict__ whb,
    const int* __restrict__ blen,
    float* __restrict__ hst, float* __restrict__ cst,
    float* __restrict__ hout, unsigned* __restrict__ bar,
    int s0, int nsteps) {
  extern __shared__ float smem[];
  float* wlds = smem;                 // [128][WROW]
  float* hlds = smem + 128 * WROW;    // [16][WROW]

  const int bc = blockIdx.x, js = blockIdx.y, dir = blockIdx.z;
  const int tid = threadIdx.x;
  const int ks = tid & 7;
  const int bg = (tid >> 3) & 3;
  const int rg = tid >> 5;            // 0..15
  const int grp = dir * 16 + bc;
  const float* wh = dir ? whb : whf;
  const float* xgp = dir ? xgb : xgf;

  // ---- stage W once per chunk (permuted rows: prow = rgs*8 + g*2 + u)
  #pragma unroll
  for (int i = 0; i < 16; ++i) {
    int f = tid + i * 512;            // float4 id 0..8191
    int prow = f >> 6;
    int k = (f & 63) << 2;
    int g = (prow >> 1) & 3, u = prow & 1, rgs = prow >> 3;
    int jg = js * 32 + rgs * 2 + u;
    float4 v = *(const float4*)(wh + ((size_t)(g * 256 + jg)) * 256 + k);
    *(float4*)&wlds[prow * WROW + k + ((k >> 5) << 2)] = v;
  }

  const int bl_th = bg * 4 + (ks & 3);      // local batch 0..15
  const int b_th = bc * 16 + bl_th;         // global batch
  const int u_th = ks >> 2;
  const int jth = js * 32 + rg * 2 + u_th;  // this thread's j
  const int cjth = jth + ((jth >> 5) << 2); // swizzled col of jth
  const int len_th = blen[b_th];
  float c0 = cst[((size_t)dir * 256 + b_th) * 256 + jth];

  // ---- prologue xq (r = 0): latency hidden under W staging
  float xq[4];
  #pragma unroll
  for (int g = 0; g < 4; ++g)
    xq[g] = xgp[(size_t)b_th * 1024 + g * 256 + jth];

  __syncthreads();   // W staged

  for (int r = 0; r < nsteps; ++r) {
    const int s = s0 + r;
    const int tt = dir ? (199 - s) : s;
    const int rslot = s & 1, wslot = 1 - rslot;

    // ---- stage h[16 b][256 k]: 2 agent-scope (sc1) dwordx4 per thread.
    const float* hsrc = hst + (((size_t)(rslot * 2 + dir)) * 256 + bc * 16) * 256;
    {
      const int f0 = tid, f1 = tid + 512;        // float4 ids
      const int b0i = f0 >> 6, k0 = (f0 & 63) << 2;
      const int b1i = f1 >> 6, k1 = (f1 & 63) << 2;
      const float* p0 = hsrc + (b0i << 8) + k0;
      const float* p1 = hsrc + (b1i << 8) + k1;
      float4 v0, v1;
      asm volatile(
          "global_load_dwordx4 %0, %2, off sc1\n\t"
          "global_load_dwordx4 %1, %3, off sc1\n\t"
          "s_waitcnt vmcnt(0)"
          : "=&v"(v0), "=&v"(v1)
          : "v"(p0), "v"(p1)
          : "memory");
      *(float4*)&hlds[b0i * WROW + k0 + ((k0 >> 5) << 2)] = v0;
      *(float4*)&hlds[b1i * WROW + k1 + ((k1 >> 5) << 2)] = v1;
    }
    __syncthreads();

    // ---- prefetch NEXT step's xq; HBM/L3 latency lands under the GEMM
    float xqn[4];
    const int rn = (r + 1 < nsteps) ? (r + 1) : r;
    #pragma unroll
    for (int g = 0; g < 4; ++g)
      xqn[g] = xgp[((size_t)rn * 256 + b_th) * 1024 + g * 256 + jth];

    // ---- GEMM: packed acc2[i][bb], lo/hi = k-even/odd partial sums
    f32x2 acc2[8][4];
    #pragma unroll
    for (int i = 0; i < 8; ++i)
      #pragma unroll
      for (int bb = 0; bb < 4; ++bb) acc2[i][bb] = (f32x2){0.f, 0.f};

    #pragma unroll
    for (int kq = 0; kq < 8; ++kq) {
      const int col = ks * 36 + kq * 4;
      float4 h4[4];
      #pragma unroll
      for (int bb = 0; bb < 4; ++bb)
        h4[bb] = *(const float4*)&hlds[(bg * 4 + bb) * WROW + col];
      f32x2 hlo[4], hhi[4];
      #pragma unroll
      for (int bb = 0; bb < 4; ++bb) {
        hlo[bb] = (f32x2){h4[bb].x, h4[bb].y};
        hhi[bb] = (f32x2){h4[bb].z, h4[bb].w};
      }
      #pragma unroll
      for (int i = 0; i < 8; ++i) {
        float4 w4 = *(const float4*)&wlds[(rg * 8 + i) * WROW + col];
        f32x2 wlo = (f32x2){w4.x, w4.y};
        f32x2 whi = (f32x2){w4.z, w4.w};
        #pragma unroll
        for (int bb = 0; bb < 4; ++bb) {
          acc2[i][bb] = __builtin_elementwise_fma(wlo, hlo[bb], acc2[i][bb]);
          acc2[i][bb] = __builtin_elementwise_fma(whi, hhi[bb], acc2[i][bb]);
        }
      }
    }

    float acc[8][4];
    #pragma unroll
    for (int i = 0; i < 8; ++i)
      #pragma unroll
      for (int bb = 0; bb < 4; ++bb)
        acc[i][bb] = acc2[i][bb].x + acc2[i][bb].y;

    // ---- butterfly over ks: xor1/xor2 route batches, xor4 finishes k-reduce
    const int bit0 = ks & 1, bit1 = (ks >> 1) & 1;
    float fin[8];
    #pragma unroll
    for (int i = 0; i < 8; ++i) {
      float k0 = bit0 ? acc[i][1] : acc[i][0];
      float s0v = bit0 ? acc[i][0] : acc[i][1];
      float k1 = bit0 ? acc[i][3] : acc[i][2];
      float s1v = bit0 ? acc[i][2] : acc[i][3];
      float r0 = k0 + __shfl_xor(s0v, 1);
      float r1 = k1 + __shfl_xor(s1v, 1);
      float k2 = bit1 ? r1 : r0;
      float s2v = bit1 ? r0 : r1;
      float r2 = k2 + __shfl_xor(s2v, 2);
      fin[i] = r2 + __shfl_xor(r2, 4);
    }

    // ---- cell update (1 cell per thread: batch b_th, hidden jth)
    float gi = fsig((u_th ? fin[1] : fin[0]) + xq[0]);
    float gf = fsig((u_th ? fin[3] : fin[2]) + xq[1]);
    float gg = ftanh((u_th ? fin[5] : fin[4]) + xq[2]);
    float go = fsig((u_th ? fin[7] : fin[6]) + xq[3]);
    float cn = gf * c0 + gi * gg;
    float hn = go * ftanh(cn);
    const bool mk = tt < len_th;
    if (mk) c0 = cn;
    float hold = hlds[bl_th * WROW + cjth];
    float hsv = mk ? hn : hold;
    __hip_atomic_store(
        hst + (((size_t)(wslot * 2 + dir)) * 256 + b_th) * 256 + jth,
        hsv, __ATOMIC_RELAXED, __HIP_MEMORY_SCOPE_AGENT);

    // ---- drain h stores (also retires xqn prefetch), signal, hout store
    // overlaps the poll.  EXACT r7 protocol — do not restructure.
    asm volatile("s_waitcnt vmcnt(0)" ::: "memory");
    __syncthreads();
    if (tid == 0)
      __hip_atomic_fetch_add(&bar[grp * 32], 1u, __ATOMIC_RELAXED,
                             __HIP_MEMORY_SCOPE_AGENT);
    hout[(((size_t)dir * 200 + tt) * 256 + b_th) * 256 + jth] = mk ? hn : 0.f;
    if (tid == 0) {
      const unsigned tgt = 8u * (unsigned)(s + 1);
      while (__hip_atomic_load(&bar[grp * 32], __ATOMIC_RELAXED,
                               __HIP_MEMORY_SCOPE_AGENT) < tgt) {}
    }
    __syncthreads();

    #pragma unroll
    for (int g = 0; g < 4; ++g) xq[g] = xqn[g];
  }

  cst[((size_t)dir * 256 + b_th) * 256 + jth] = c0;
}

// ---------------- feats[b][t][k] = [hf|hb] . W_tag[k] + b_tag[k]
// r10: pk-FMA with lo/hi k-split partial sums.
__global__ __launch_bounds__(256) void feats_kernel(
    const float* __restrict__ h_out, const float* __restrict__ wtag,
    const float* __restrict__ btag, float* __restrict__ feats) {
  __shared__ float hcat[32][512];
  const int t = blockIdx.x, bc = blockIdx.y;
  const int tid = threadIdx.x;
  const float* hf = h_out + (((size_t)0 * 200 + t) * 256 + bc * 32) * 256;
  const float* hb = h_out + (((size_t)1 * 200 + t) * 256 + bc * 32) * 256;
  for (int i = tid; i < 2048; i += 256) {
    int row = i >> 6, c4 = (i & 63) << 2;
    *(float4*)&hcat[row][c4] = *(const float4*)(hf + (size_t)row * 256 + c4);
    *(float4*)&hcat[row][256 + c4] = *(const float4*)(hb + (size_t)row * 256 + c4);
  }
  __syncthreads();
  const int kk = tid & 63;
  const int bg = tid >> 6;
  if (kk < 52) {
    f32x2 acc2[8];
    #pragma unroll
    for (int i = 0; i < 8; ++i) acc2[i] = (f32x2){0.f, 0.f};
    const float* wr = wtag + (size_t)kk * 512;
    for (int jq = 0; jq < 128; ++jq) {
      float4 wv = *(const float4*)(wr + jq * 4);
      f32x2 wlo = (f32x2){wv.x, wv.y};
      f32x2 whi = (f32x2){wv.z, wv.w};
      #pragma unroll
      for (int bi = 0; bi < 8; ++bi) {
        float4 hv = *(const float4*)&hcat[bg * 8 + bi][jq * 4];
        f32x2 hlo = (f32x2){hv.x, hv.y};
        f32x2 hhi = (f32x2){hv.z, hv.w};
        acc2[bi] = __builtin_elementwise_fma(wlo, hlo, acc2[bi]);
        acc2[bi] = __builtin_elementwise_fma(whi, hhi, acc2[bi]);
      }
    }
    float bv = btag[kk];
    #pragma unroll
    for (int bi = 0; bi < 8; ++bi)
      feats[(size_t)(bc * 32 + bg * 8 + bi) * 10400 + t * 52 + kk] =
          acc2[bi].x + acc2[bi].y + bv;
  }
}

// ---------------- Viterbi v3 (r7, passed): one WAVE per batch row.
__global__ __launch_bounds__(64) void viterbi_kernel(
    const float* __restrict__ feats, const float* __restrict__ trans,
    const int* __restrict__ blen, float* __restrict__ out) {
  __shared__ float flds[10400];
  __shared__ float pl[56];
  __shared__ unsigned char bp[199 * 52];

  const int b = blockIdx.x;
  const int lane = threadIdx.x;
  const int kk = (lane < 52) ? lane : 0;
  const float* fb = feats + (size_t)b * 10400;
  const int len = blen[b];

  for (int i = lane; i < 2600; i += 64)
    *(float4*)&flds[i * 4] = *(const float4*)(fb + i * 4);

  float trc[52];
  #pragma unroll
  for (int j = 0; j < 52; ++j) trc[j] = trans[j * 52 + kk];
  __syncthreads();

  float part = trans[50 * 52 + kk] + flds[kk];   // START row = 50
  if (lane < 52) pl[lane] = part;

  for (int t = 1; t < 200; ++t) {
    const float ftk = flds[t * 52 + kk];
    float pa[52];
    #pragma unroll
    for (int q = 0; q < 13; ++q) {
      float4 v = *(const float4*)&pl[q * 4];
      pa[q * 4 + 0] = v.x; pa[q * 4 + 1] = v.y;
      pa[q * 4 + 2] = v.z; pa[q * 4 + 3] = v.w;
    }
    float mv0 = -1e30f, mv1 = -1e30f, mv2 = -1e30f, mv3 = -1e30f;
    int mj0 = 0, mj1 = 13, mj2 = 26, mj3 = 39;
    #pragma unroll
    for (int q = 0; q < 13; ++q) {
      float c0v = (pa[q] + trc[q]) + ftk;
      if (c0v > mv0) { mv0 = c0v; mj0 = q; }
      float c1v = (pa[13 + q] + trc[13 + q]) + ftk;
      if (c1v > mv1) { mv1 = c1v; mj1 = 13 + q; }
      float c2v = (pa[26 + q] + trc[26 + q]) + ftk;
      if (c2v > mv2) { mv2 = c2v; mj2 = 26 + q; }
      float c3v = (pa[39 + q] + trc[39 + q]) + ftk;
      if (c3v > mv3) { mv3 = c3v; mj3 = 39 + q; }
    }
    float mv = mv0; int mj = mj0;
    if (mv1 > mv) { mv = mv1; mj = mj1; }
    if (mv2 > mv) { mv = mv2; mj = mj2; }
    if (mv3 > mv) { mv = mv3; mj = mj3; }
    const bool m = t < len;
    if (lane < 52) {
      bp[(t - 1) * 52 + lane] = (unsigned char)(m ? mj : lane);
      if (m) { part = mv; pl[lane] = mv; }
    }
  }

  float fin = (lane < 52) ? (part + trans[lane * 52 + 51]) : -1e30f;
  int bi = lane;
  #pragma unroll
  for (int off = 32; off; off >>= 1) {
    float ov = __shfl_down(fin, off);
    int oi = __shfl_down(bi, off);
    if (ov > fin || (ov == fin && oi < bi)) { fin = ov; bi = oi; }
  }
  if (lane == 0) {
    out[b] = fin;
    int tag = bi;
    float* dec = out + 256 + (size_t)b * 200;
    dec[199] = (199 < len) ? (float)tag : 0.f;
    for (int i = 198; i >= 0; --i) {
      tag = bp[i * 52 + tag];
      dec[i] = (i < len) ? (float)tag : 0.f;
    }
  }
}

extern "C" void kernel_launch(void* const* d_in, const int* in_sizes, int n_in,
                              void* d_out, int out_size, void* d_ws, size_t ws_size,
                              hipStream_t stream) {
  const int*   bin  = (const int*)d_in[0];
  const int*   bfe  = (const int*)d_in[1];
  const int*   blen = (const int*)d_in[2];
  const float* ctab = (const float*)d_in[5];
  const float* ftab = (const float*)d_in[6];
  const float* wihf = (const float*)d_in[7];
  const float* whhf = (const float*)d_in[8];
  const float* bf   = (const float*)d_in[9];
  const float* wihb = (const float*)d_in[10];
  const float* whhb = (const float*)d_in[11];
  const float* bb   = (const float*)d_in[12];
  const float* wtag = (const float*)d_in[13];
  const float* btag = (const float*)d_in[14];
  const float* trn  = (const float*)d_in[15];

  (void)hipFuncSetAttribute(reinterpret_cast<const void*>(lstm_chunk),
                            hipFuncAttributeMaxDynamicSharedMemorySize,
                            SMEM_BYTES);

  const size_t FIXED_F = 29271040;
  size_t ws_f = ws_size / sizeof(float);
  int C = 1;
  const int cands[10] = {50, 40, 25, 20, 10, 8, 5, 4, 2, 1};
  for (int u = 0; u < 10; ++u) {
    if (FIXED_F + (size_t)2 * cands[u] * 262144 <= ws_f) { C = cands[u]; break; }
  }

  float* ws  = (float*)d_ws;
  float* xgf = ws;
  float* xgb = xgf + (size_t)C * 262144;
  float* hst = xgb + (size_t)C * 262144;    // 2 slots x 2 dir x 256 x 256
  float* cst = hst + 262144;
  float* hout = cst + 131072;               // 2 dir x 200 x 256 x 256
  float* fts  = hout + 26214400;
  unsigned* bar = (unsigned*)(fts + 2662400); // 32 groups x stride 32
  float* out  = (float*)d_out;

  hipMemsetAsync(hst, 0, (size_t)(262144 + 131072) * sizeof(float), stream);
  hipMemsetAsync(bar, 0, 1024 * sizeof(unsigned), stream);

  const int nchunks = 200 / C;
  for (int c = 0; c < nchunks; ++c) {
    xg_gemm<<<dim3(2 * C, 8), 256, 0, stream>>>(bin, bfe, blen, ctab, ftab,
                                                wihf, bf, xgf, c * C, 1);
    xg_gemm<<<dim3(2 * C, 8), 256, 0, stream>>>(bin, bfe, blen, ctab, ftab,
                                                wihb, bb, xgb, 199 - c * C, -1);
    lstm_chunk<<<dim3(16, 8, 2), 512, SMEM_BYTES, stream>>>(
        xgf, xgb, whhf, whhb, blen, hst, cst, hout, bar, c * C, C);
  }
  feats_kernel<<<dim3(200, 8), 256, 0, stream>>>(hout, wtag, btag, fts);
  viterbi_kernel<<<256, 64, 0, stream>>>(fts, trn, blen, out);
}

// Round 4
// 2218.030 us; speedup vs baseline: 2.7202x; 1.0111x over previous
//
#include <hip/hip_runtime.h>
#include <math.h>

#define T_ 200
#define WROW 284                       // LDS row stride (256 + swizzle room)
#define SMEM_FLOATS (128 * WROW + 16 * WROW)
#define SMEM_BYTES (SMEM_FLOATS * 4)   // 163,584 <= 163,840 (160 KiB)

typedef float f32x2 __attribute__((ext_vector_type(2)));

__device__ __forceinline__ float fsig(float x) {
  return 1.f / (1.f + __expf(-x));
}
__device__ __forceinline__ float ftanh(float x) {
  return 1.f - 2.f / (__expf(2.f * x) + 1.f);   // exact at +-inf, no NaN
}
// DPP cross-lane adds on the VALU pipe (no LDS/lgkm): quad_perm xor1/xor2.
__device__ __forceinline__ float dpp_xor1(float x) {
  return __int_as_float(__builtin_amdgcn_update_dpp(
      0, __float_as_int(x), 0xB1, 0xF, 0xF, true));   // [1,0,3,2]
}
__device__ __forceinline__ float dpp_xor2(float x) {
  return __int_as_float(__builtin_amdgcn_update_dpp(
      0, __float_as_int(x), 0x4E, 0xF, 0xF, true));   // [2,3,0,1]
}

// ---------------- xg GEMM v3 (r10, proven): 128x128 tile, 8x8 micro, fused
// embedding gather, masked-tile early exit, pk-FMA inner loop.
__global__ __launch_bounds__(256) void xg_gemm(
    const int* __restrict__ bin, const int* __restrict__ bfe,
    const int* __restrict__ blen,
    const float* __restrict__ ctab, const float* __restrict__ ftab,
    const float* __restrict__ wih, const float* __restrict__ bias,
    float* __restrict__ xgslot, int t0, int sgn) {
  const int m0 = blockIdx.x * 128;
  const int rloc = m0 >> 8;
  const int t_blk = t0 + sgn * rloc;
  if (t_blk >= blen[m0 & 255]) return;   // fully masked tile (sorted lengths)

  __shared__ float As[32][140];   // [k][m swizzled]
  __shared__ float Bs[32][132];   // [k][n]
  const int tid = threadIdx.x;
  const int n0 = blockIdx.y * 128;
  const int mm = tid & 15;
  const int nn = tid >> 4;

  const int ra = tid & 127;            // staging row (A: m, B: n)
  const int ka = (tid >> 7) << 4;      // k-offset 0 or 16

  const int bcol = (m0 + ra) & 255;
  const float* cr = ctab + ((size_t)bin[bcol * T_ + t_blk] << 8);
  const float* fr = ftab + ((size_t)bfe[bcol * T_ + t_blk] << 8);
  const float* br = wih + (size_t)(n0 + ra) * 256;
  const int cwa = ra + ((ra >> 5) << 2);   // swizzled A col for m=ra

  f32x2 acc[8][4];                      // [i][j-pair]
  #pragma unroll
  for (int i = 0; i < 8; ++i)
    #pragma unroll
    for (int j = 0; j < 4; ++j) acc[i][j] = (f32x2){0.f, 0.f};

  const int am0 = mm * 8 + ((mm >> 2) << 2);   // swizzled base col for A reads
  const int bn0 = nn * 8;

  for (int ks = 0; ks < 256; ks += 32) {
    float4 c4[4], f4v[4], b4[4];
    #pragma unroll
    for (int w = 0; w < 4; ++w) {
      c4[w]  = *(const float4*)(cr + ks + ka + w * 4);
      f4v[w] = *(const float4*)(fr + ks + ka + w * 4);
      b4[w]  = *(const float4*)(br + ks + ka + w * 4);
    }
    __syncthreads();   // previous iteration's consumers done
    #pragma unroll
    for (int w = 0; w < 4; ++w) {
      int kk = ka + w * 4;
      As[kk + 0][cwa] = c4[w].x * f4v[w].x;
      As[kk + 1][cwa] = c4[w].y * f4v[w].y;
      As[kk + 2][cwa] = c4[w].z * f4v[w].z;
      As[kk + 3][cwa] = c4[w].w * f4v[w].w;
      Bs[kk + 0][ra] = b4[w].x;
      Bs[kk + 1][ra] = b4[w].y;
      Bs[kk + 2][ra] = b4[w].z;
      Bs[kk + 3][ra] = b4[w].w;
    }
    __syncthreads();
    #pragma unroll 4
    for (int k = 0; k < 32; ++k) {
      float4 a0 = *(const float4*)&As[k][am0];
      float4 a1 = *(const float4*)&As[k][am0 + 4];
      float4 b0 = *(const float4*)&Bs[k][bn0];
      float4 b1 = *(const float4*)&Bs[k][bn0 + 4];
      float am[8] = {a0.x, a0.y, a0.z, a0.w, a1.x, a1.y, a1.z, a1.w};
      f32x2 bp[4] = {{b0.x, b0.y}, {b0.z, b0.w}, {b1.x, b1.y}, {b1.z, b1.w}};
      #pragma unroll
      for (int i = 0; i < 8; ++i) {
        f32x2 av = {am[i], am[i]};
        #pragma unroll
        for (int j = 0; j < 4; ++j)
          acc[i][j] = __builtin_elementwise_fma(av, bp[j], acc[i][j]);
      }
    }
  }

  float4 bv0 = *(const float4*)(bias + n0 + bn0);
  float4 bv1 = *(const float4*)(bias + n0 + bn0 + 4);
  #pragma unroll
  for (int i = 0; i < 8; ++i) {
    int row = m0 + mm * 8 + i;
    float4 o0, o1;
    o0.x = acc[i][0].x + bv0.x; o0.y = acc[i][0].y + bv0.y;
    o0.z = acc[i][1].x + bv0.z; o0.w = acc[i][1].y + bv0.w;
    o1.x = acc[i][2].x + bv1.x; o1.y = acc[i][2].y + bv1.y;
    o1.z = acc[i][3].x + bv1.z; o1.w = acc[i][3].y + bv1.w;
    *(float4*)(xgslot + (size_t)row * 1024 + n0 + bn0) = o0;
    *(float4*)(xgslot + (size_t)row * 1024 + n0 + bn0 + 4) = o1;
  }
}

// ---------------- persistent LSTM chunk: r7-proven v4 protocol (3x
// syncthreads, tid0 fetch_add + tid0 poll, agent-scope sc1 h exchange) +
// r9 xq-prefetch + r10 pk-FMA. r11: (a) W ds_reads software-pipelined one kq
// ahead (hides lgkm latency under FMAs), (b) butterfly xor1/xor2 via DPP
// (VALU pipe) instead of ds_swizzle (LDS pipe).
__global__ __launch_bounds__(512, 1) void lstm_chunk(
    const float* __restrict__ xgf, const float* __restrict__ xgb,
    const float* __restrict__ whf, const float* __restrict__ whb,
    const int* __restrict__ blen,
    float* __restrict__ hst, float* __restrict__ cst,
    float* __restrict__ hout, unsigned* __restrict__ bar,
    int s0, int nsteps) {
  extern __shared__ float smem[];
  float* wlds = smem;                 // [128][WROW]
  float* hlds = smem + 128 * WROW;    // [16][WROW]

  const int bc = blockIdx.x, js = blockIdx.y, dir = blockIdx.z;
  const int tid = threadIdx.x;
  const int ks = tid & 7;
  const int bg = (tid >> 3) & 3;
  const int rg = tid >> 5;            // 0..15
  const int grp = dir * 16 + bc;
  const float* wh = dir ? whb : whf;
  const float* xgp = dir ? xgb : xgf;

  // ---- stage W once per chunk (permuted rows: prow = rgs*8 + g*2 + u)
  #pragma unroll
  for (int i = 0; i < 16; ++i) {
    int f = tid + i * 512;            // float4 id 0..8191
    int prow = f >> 6;
    int k = (f & 63) << 2;
    int g = (prow >> 1) & 3, u = prow & 1, rgs = prow >> 3;
    int jg = js * 32 + rgs * 2 + u;
    float4 v = *(const float4*)(wh + ((size_t)(g * 256 + jg)) * 256 + k);
    *(float4*)&wlds[prow * WROW + k + ((k >> 5) << 2)] = v;
  }

  const int bl_th = bg * 4 + (ks & 3);      // local batch 0..15
  const int b_th = bc * 16 + bl_th;         // global batch
  const int u_th = ks >> 2;
  const int jth = js * 32 + rg * 2 + u_th;  // this thread's j
  const int cjth = jth + ((jth >> 5) << 2); // swizzled col of jth
  const int len_th = blen[b_th];
  float c0 = cst[((size_t)dir * 256 + b_th) * 256 + jth];

  // ---- prologue xq (r = 0): latency hidden under W staging
  float xq[4];
  #pragma unroll
  for (int g = 0; g < 4; ++g)
    xq[g] = xgp[(size_t)b_th * 1024 + g * 256 + jth];

  __syncthreads();   // W staged

  for (int r = 0; r < nsteps; ++r) {
    const int s = s0 + r;
    const int tt = dir ? (199 - s) : s;
    const int rslot = s & 1, wslot = 1 - rslot;

    // ---- stage h[16 b][256 k]: 2 agent-scope (sc1) dwordx4 per thread.
    const float* hsrc = hst + (((size_t)(rslot * 2 + dir)) * 256 + bc * 16) * 256;
    {
      const int f0 = tid, f1 = tid + 512;        // float4 ids
      const int b0i = f0 >> 6, k0 = (f0 & 63) << 2;
      const int b1i = f1 >> 6, k1 = (f1 & 63) << 2;
      const float* p0 = hsrc + (b0i << 8) + k0;
      const float* p1 = hsrc + (b1i << 8) + k1;
      float4 v0, v1;
      asm volatile(
          "global_load_dwordx4 %0, %2, off sc1\n\t"
          "global_load_dwordx4 %1, %3, off sc1\n\t"
          "s_waitcnt vmcnt(0)"
          : "=&v"(v0), "=&v"(v1)
          : "v"(p0), "v"(p1)
          : "memory");
      *(float4*)&hlds[b0i * WROW + k0 + ((k0 >> 5) << 2)] = v0;
      *(float4*)&hlds[b1i * WROW + k1 + ((k1 >> 5) << 2)] = v1;
    }
    __syncthreads();

    // ---- prefetch NEXT step's xq; HBM/L3 latency lands under the GEMM
    float xqn[4];
    const int rn = (r + 1 < nsteps) ? (r + 1) : r;
    #pragma unroll
    for (int g = 0; g < 4; ++g)
      xqn[g] = xgp[((size_t)rn * 256 + b_th) * 1024 + g * 256 + jth];

    // ---- GEMM: packed acc2[i][bb], lo/hi = k-even/odd partial sums.
    // W reads pipelined one kq ahead so lgkm latency hides under FMAs.
    f32x2 acc2[8][4];
    #pragma unroll
    for (int i = 0; i < 8; ++i)
      #pragma unroll
      for (int bb = 0; bb < 4; ++bb) acc2[i][bb] = (f32x2){0.f, 0.f};

    float4 w4c[8];
    #pragma unroll
    for (int i = 0; i < 8; ++i)
      w4c[i] = *(const float4*)&wlds[(rg * 8 + i) * WROW + ks * 36];

    #pragma unroll
    for (int kq = 0; kq < 8; ++kq) {
      const int col = ks * 36 + kq * 4;
      float4 h4[4];
      #pragma unroll
      for (int bb = 0; bb < 4; ++bb)
        h4[bb] = *(const float4*)&hlds[(bg * 4 + bb) * WROW + col];
      float4 w4n[8];
      if (kq < 7) {
        #pragma unroll
        for (int i = 0; i < 8; ++i)
          w4n[i] = *(const float4*)&wlds[(rg * 8 + i) * WROW + col + 4];
      }
      f32x2 hlo[4], hhi[4];
      #pragma unroll
      for (int bb = 0; bb < 4; ++bb) {
        hlo[bb] = (f32x2){h4[bb].x, h4[bb].y};
        hhi[bb] = (f32x2){h4[bb].z, h4[bb].w};
      }
      #pragma unroll
      for (int i = 0; i < 8; ++i) {
        f32x2 wlo = (f32x2){w4c[i].x, w4c[i].y};
        f32x2 whi = (f32x2){w4c[i].z, w4c[i].w};
        #pragma unroll
        for (int bb = 0; bb < 4; ++bb) {
          acc2[i][bb] = __builtin_elementwise_fma(wlo, hlo[bb], acc2[i][bb]);
          acc2[i][bb] = __builtin_elementwise_fma(whi, hhi[bb], acc2[i][bb]);
        }
      }
      if (kq < 7) {
        #pragma unroll
        for (int i = 0; i < 8; ++i) w4c[i] = w4n[i];
      }
    }

    float acc[8][4];
    #pragma unroll
    for (int i = 0; i < 8; ++i)
      #pragma unroll
      for (int bb = 0; bb < 4; ++bb)
        acc[i][bb] = acc2[i][bb].x + acc2[i][bb].y;

    // ---- butterfly over ks: xor1/xor2 (DPP, VALU pipe) route batches,
    // xor4 (ds_swizzle) finishes the k-reduce.
    const int bit0 = ks & 1, bit1 = (ks >> 1) & 1;
    float fin[8];
    #pragma unroll
    for (int i = 0; i < 8; ++i) {
      float k0 = bit0 ? acc[i][1] : acc[i][0];
      float s0v = bit0 ? acc[i][0] : acc[i][1];
      float k1 = bit0 ? acc[i][3] : acc[i][2];
      float s1v = bit0 ? acc[i][2] : acc[i][3];
      float r0 = k0 + dpp_xor1(s0v);
      float r1 = k1 + dpp_xor1(s1v);
      float k2 = bit1 ? r1 : r0;
      float s2v = bit1 ? r0 : r1;
      float r2 = k2 + dpp_xor2(s2v);
      fin[i] = r2 + __shfl_xor(r2, 4);
    }

    // ---- cell update (1 cell per thread: batch b_th, hidden jth)
    float gi = fsig((u_th ? fin[1] : fin[0]) + xq[0]);
    float gf = fsig((u_th ? fin[3] : fin[2]) + xq[1]);
    float gg = ftanh((u_th ? fin[5] : fin[4]) + xq[2]);
    float go = fsig((u_th ? fin[7] : fin[6]) + xq[3]);
    float cn = gf * c0 + gi * gg;
    float hn = go * ftanh(cn);
    const bool mk = tt < len_th;
    if (mk) c0 = cn;
    float hold = hlds[bl_th * WROW + cjth];
    float hsv = mk ? hn : hold;
    __hip_atomic_store(
        hst + (((size_t)(wslot * 2 + dir)) * 256 + b_th) * 256 + jth,
        hsv, __ATOMIC_RELAXED, __HIP_MEMORY_SCOPE_AGENT);

    // ---- drain h stores (also retires xqn prefetch), signal, hout store
    // overlaps the poll.  EXACT r7 protocol — do not restructure.
    asm volatile("s_waitcnt vmcnt(0)" ::: "memory");
    __syncthreads();
    if (tid == 0)
      __hip_atomic_fetch_add(&bar[grp * 32], 1u, __ATOMIC_RELAXED,
                             __HIP_MEMORY_SCOPE_AGENT);
    hout[(((size_t)dir * 200 + tt) * 256 + b_th) * 256 + jth] = mk ? hn : 0.f;
    if (tid == 0) {
      const unsigned tgt = 8u * (unsigned)(s + 1);
      while (__hip_atomic_load(&bar[grp * 32], __ATOMIC_RELAXED,
                               __HIP_MEMORY_SCOPE_AGENT) < tgt) {}
    }
    __syncthreads();

    #pragma unroll
    for (int g = 0; g < 4; ++g) xq[g] = xqn[g];
  }

  cst[((size_t)dir * 256 + b_th) * 256 + jth] = c0;
}

// ---------------- feats[b][t][k] = [hf|hb] . W_tag[k] + b_tag[k]
// r11: early-exit fully-masked (t, batch-tile) blocks. Skipped feats are only
// read by viterbi at masked positions, which it never commits (and with the
// r11 viterbi it does not even load them).
__global__ __launch_bounds__(256) void feats_kernel(
    const float* __restrict__ h_out, const float* __restrict__ wtag,
    const float* __restrict__ btag, float* __restrict__ feats,
    const int* __restrict__ blen) {
  const int t = blockIdx.x, bc = blockIdx.y;
  if (t >= blen[bc * 32]) return;   // sorted lengths: tile max is first row
  __shared__ float hcat[32][512];
  const int tid = threadIdx.x;
  const float* hf = h_out + (((size_t)0 * 200 + t) * 256 + bc * 32) * 256;
  const float* hb = h_out + (((size_t)1 * 200 + t) * 256 + bc * 32) * 256;
  for (int i = tid; i < 2048; i += 256) {
    int row = i >> 6, c4 = (i & 63) << 2;
    *(float4*)&hcat[row][c4] = *(const float4*)(hf + (size_t)row * 256 + c4);
    *(float4*)&hcat[row][256 + c4] = *(const float4*)(hb + (size_t)row * 256 + c4);
  }
  __syncthreads();
  const int kk = tid & 63;
  const int bg = tid >> 6;
  if (kk < 52) {
    f32x2 acc2[8];
    #pragma unroll
    for (int i = 0; i < 8; ++i) acc2[i] = (f32x2){0.f, 0.f};
    const float* wr = wtag + (size_t)kk * 512;
    for (int jq = 0; jq < 128; ++jq) {
      float4 wv = *(const float4*)(wr + jq * 4);
      f32x2 wlo = (f32x2){wv.x, wv.y};
      f32x2 whi = (f32x2){wv.z, wv.w};
      #pragma unroll
      for (int bi = 0; bi < 8; ++bi) {
        float4 hv = *(const float4*)&hcat[bg * 8 + bi][jq * 4];
        f32x2 hlo = (f32x2){hv.x, hv.y};
        f32x2 hhi = (f32x2){hv.z, hv.w};
        acc2[bi] = __builtin_elementwise_fma(wlo, hlo, acc2[bi]);
        acc2[bi] = __builtin_elementwise_fma(whi, hhi, acc2[bi]);
      }
    }
    float bv = btag[kk];
    #pragma unroll
    for (int bi = 0; bi < 8; ++bi)
      feats[(size_t)(bc * 32 + bg * 8 + bi) * 10400 + t * 52 + kk] =
          acc2[bi].x + acc2[bi].y + bv;
  }
}

// ---------------- Viterbi v4 (r11): one WAVE per batch row; serial loops
// capped at len (mask is always true inside, identity beyond — exploited).
__global__ __launch_bounds__(64) void viterbi_kernel(
    const float* __restrict__ feats, const float* __restrict__ trans,
    const int* __restrict__ blen, float* __restrict__ out) {
  __shared__ float flds[10400];
  __shared__ float pl[56];
  __shared__ unsigned char bp[199 * 52];

  const int b = blockIdx.x;
  const int lane = threadIdx.x;
  const int kk = (lane < 52) ? lane : 0;
  const float* fb = feats + (size_t)b * 10400;
  const int len = blen[b];

  const int nf4 = (len * 52 + 3) >> 2;   // only the live prefix of feats
  for (int i = lane; i < nf4; i += 64)
    *(float4*)&flds[i * 4] = *(const float4*)(fb + i * 4);

  float trc[52];
  #pragma unroll
  for (int j = 0; j < 52; ++j) trc[j] = trans[j * 52 + kk];
  __syncthreads();

  float part = trans[50 * 52 + kk] + flds[kk];   // START row = 50
  if (lane < 52) pl[lane] = part;

  for (int t = 1; t < len; ++t) {   // all iterations unmasked by construction
    const float ftk = flds[t * 52 + kk];
    float pa[52];
    #pragma unroll
    for (int q = 0; q < 13; ++q) {
      float4 v = *(const float4*)&pl[q * 4];
      pa[q * 4 + 0] = v.x; pa[q * 4 + 1] = v.y;
      pa[q * 4 + 2] = v.z; pa[q * 4 + 3] = v.w;
    }
    float mv0 = -1e30f, mv1 = -1e30f, mv2 = -1e30f, mv3 = -1e30f;
    int mj0 = 0, mj1 = 13, mj2 = 26, mj3 = 39;
    #pragma unroll
    for (int q = 0; q < 13; ++q) {
      float c0v = (pa[q] + trc[q]) + ftk;
      if (c0v > mv0) { mv0 = c0v; mj0 = q; }
      float c1v = (pa[13 + q] + trc[13 + q]) + ftk;
      if (c1v > mv1) { mv1 = c1v; mj1 = 13 + q; }
      float c2v = (pa[26 + q] + trc[26 + q]) + ftk;
      if (c2v > mv2) { mv2 = c2v; mj2 = 26 + q; }
      float c3v = (pa[39 + q] + trc[39 + q]) + ftk;
      if (c3v > mv3) { mv3 = c3v; mj3 = 39 + q; }
    }
    float mv = mv0; int mj = mj0;
    if (mv1 > mv) { mv = mv1; mj = mj1; }
    if (mv2 > mv) { mv = mv2; mj = mj2; }
    if (mv3 > mv) { mv = mv3; mj = mj3; }
    if (lane < 52) {
      bp[(t - 1) * 52 + lane] = (unsigned char)mj;
      part = mv; pl[lane] = mv;
    }
  }

  float fin = (lane < 52) ? (part + trans[lane * 52 + 51]) : -1e30f;
  int bi = lane;
  #pragma unroll
  for (int off = 32; off; off >>= 1) {
    float ov = __shfl_down(fin, off);
    int oi = __shfl_down(bi, off);
    if (ov > fin || (ov == fin && oi < bi)) { fin = ov; bi = oi; }
  }
  if (lane == 0) {
    out[b] = fin;
    float* dec = out + 256 + (size_t)b * 200;
    for (int i = len; i < 200; ++i) dec[i] = 0.f;   // masked tail
    int tag = bi;
    dec[len - 1] = (float)tag;                       // == bi (identity beyond)
    for (int i = len - 2; i >= 0; --i) {
      tag = bp[i * 52 + tag];                        // bp[i] real for i<=len-2
      dec[i] = (float)tag;
    }
  }
}

extern "C" void kernel_launch(void* const* d_in, const int* in_sizes, int n_in,
                              void* d_out, int out_size, void* d_ws, size_t ws_size,
                              hipStream_t stream) {
  const int*   bin  = (const int*)d_in[0];
  const int*   bfe  = (const int*)d_in[1];
  const int*   blen = (const int*)d_in[2];
  const float* ctab = (const float*)d_in[5];
  const float* ftab = (const float*)d_in[6];
  const float* wihf = (const float*)d_in[7];
  const float* whhf = (const float*)d_in[8];
  const float* bf   = (const float*)d_in[9];
  const float* wihb = (const float*)d_in[10];
  const float* whhb = (const float*)d_in[11];
  const float* bb   = (const float*)d_in[12];
  const float* wtag = (const float*)d_in[13];
  const float* btag = (const float*)d_in[14];
  const float* trn  = (const float*)d_in[15];

  (void)hipFuncSetAttribute(reinterpret_cast<const void*>(lstm_chunk),
                            hipFuncAttributeMaxDynamicSharedMemorySize,
                            SMEM_BYTES);

  const size_t FIXED_F = 29271040;
  size_t ws_f = ws_size / sizeof(float);
  int C = 1;
  const int cands[10] = {50, 40, 25, 20, 10, 8, 5, 4, 2, 1};
  for (int u = 0; u < 10; ++u) {
    if (FIXED_F + (size_t)2 * cands[u] * 262144 <= ws_f) { C = cands[u]; break; }
  }

  float* ws  = (float*)d_ws;
  float* xgf = ws;
  float* xgb = xgf + (size_t)C * 262144;
  float* hst = xgb + (size_t)C * 262144;    // 2 slots x 2 dir x 256 x 256
  float* cst = hst + 262144;
  float* hout = cst + 131072;               // 2 dir x 200 x 256 x 256
  float* fts  = hout + 26214400;
  unsigned* bar = (unsigned*)(fts + 2662400); // 32 groups x stride 32
  float* out  = (float*)d_out;

  hipMemsetAsync(hst, 0, (size_t)(262144 + 131072) * sizeof(float), stream);
  hipMemsetAsync(bar, 0, 1024 * sizeof(unsigned), stream);

  const int nchunks = 200 / C;
  for (int c = 0; c < nchunks; ++c) {
    xg_gemm<<<dim3(2 * C, 8), 256, 0, stream>>>(bin, bfe, blen, ctab, ftab,
                                                wihf, bf, xgf, c * C, 1);
    xg_gemm<<<dim3(2 * C, 8), 256, 0, stream>>>(bin, bfe, blen, ctab, ftab,
                                                wihb, bb, xgb, 199 - c * C, -1);
    lstm_chunk<<<dim3(16, 8, 2), 512, SMEM_BYTES, stream>>>(
        xgf, xgb, whhf, whhb, blen, hst, cst, hout, bar, c * C, C);
  }
  feats_kernel<<<dim3(200, 8), 256, 0, stream>>>(hout, wtag, btag, fts, blen);
  viterbi_kernel<<<256, 64, 0, stream>>>(fts, trn, blen, out);
}